// Round 1
// baseline (334.538 us; speedup 1.0000x reference)
//
#include <hip/hip_runtime.h>
#include <math.h>

#define C_DIM 256
#define HWDIM 256
#define PATCH_SZ 8
#define R_DIM 32          // C / r
#define NPIX 64           // pixels per patch
#define PAD 65            // LDS row pitch (floats) to kill bank conflicts

__global__ __launch_bounds__(256, 2)
void lpa_fused_kernel(const float* __restrict__ x,
                      const float* __restrict__ gamma,
                      const float* __restrict__ beta,
                      const float* __restrict__ w1,
                      const float* __restrict__ w2,
                      float* __restrict__ out,
                      int nwg)
{
    // 72 KiB static LDS -> 2 blocks/CU
    __shared__ float xs[C_DIM * PAD];        // patch data [c][p], padded
    __shared__ float part_s[4 * NPIX];
    __shared__ float part_q[4 * NPIX];
    __shared__ float mu_s[NPIX];
    __shared__ float rs_s[NPIX];
    __shared__ float pm_s[C_DIM];
    __shared__ float h_s[R_DIM];
    __shared__ float A_s[C_DIM];             // gamma[c] * gate[c]
    __shared__ float B_s[C_DIM];             // beta[c]  * gate[c]

    const int t = threadIdx.x;
    const int bid = blockIdx.x;

    // XCD-aware bijective swizzle: consecutive patches stay on one XCD's L2
    // (nwg is always a multiple of 8 here: B*1024)
    const int per_xcd = nwg >> 3;
    const int pid = (bid & 7) * per_xcd + (bid >> 3);

    const int b  = pid >> 10;                // 1024 patches per batch image
    const int ij = pid & 1023;
    const unsigned H0 = (unsigned)(ij >> 5) * PATCH_SZ;   // patch row origin
    const unsigned W0 = (unsigned)(ij & 31) * PATCH_SZ;   // patch col origin

    const unsigned baseb = (unsigned)b * C_DIM * HWDIM * HWDIM;

    // ---- Stage 1: load patch (256 channels x 64 pixels) into LDS ----
    // idx = c*16 + h*2 + half ; each thread does 16 float4 loads
#pragma unroll
    for (int it = 0; it < 16; ++it) {
        unsigned idx  = (unsigned)(it * 256 + t);
        unsigned c    = idx >> 4;
        unsigned h    = (idx >> 1) & 7;
        unsigned half = idx & 1;
        unsigned goff = baseb + (c * HWDIM + H0 + h) * HWDIM + W0 + half * 4u;
        float4 v = *reinterpret_cast<const float4*>(x + goff);
        float* dst = &xs[c * PAD + h * 8 + half * 4];
        dst[0] = v.x; dst[1] = v.y; dst[2] = v.z; dst[3] = v.w;
    }
    __syncthreads();

    // ---- Stage 2: per-pixel LN stats (sum, sumsq over 256 channels) ----
    {
        const int p = t & 63;
        const int g = t >> 6;
        const int cbase = g * 64;
        float s = 0.f, q = 0.f;
#pragma unroll 8
        for (int cc = 0; cc < 64; ++cc) {
            float v = xs[(cbase + cc) * PAD + p];
            s += v;
            q += v * v;
        }
        part_s[g * 64 + p] = s;
        part_q[g * 64 + p] = q;
    }
    __syncthreads();
    if (t < 64) {
        float s = part_s[t] + part_s[64 + t] + part_s[128 + t] + part_s[192 + t];
        float q = part_q[t] + part_q[64 + t] + part_q[128 + t] + part_q[192 + t];
        float mu  = s * (1.0f / 256.0f);
        float var = q * (1.0f / 256.0f) - mu * mu;
        mu_s[t] = mu;
        rs_s[t] = rsqrtf(var + 1e-5f);
    }
    __syncthreads();

    // ---- Stage 3: per-channel patch mean of normalized values ----
    float g_c, b_c;
    {
        const int c = t;                     // 256 threads = 256 channels
        g_c = gamma[c];
        b_c = beta[c];
        float s = 0.f;
#pragma unroll 8
        for (int p = 0; p < 64; ++p) {
            s += rs_s[p] * (xs[c * PAD + p] - mu_s[p]);
        }
        pm_s[c] = g_c * s * (1.0f / 64.0f) + b_c;
    }
    __syncthreads();

    // ---- Stage 4a: h = silu(w1 @ pm), w1 is [32][256] row-major ----
    {
        const int r = t >> 3;                // output row 0..31
        const int k = t & 7;                 // 8-way split of the dot
        const float4* wrow = reinterpret_cast<const float4*>(w1 + r * C_DIM + k * 32);
        const float* pmk = &pm_s[k * 32];
        float s = 0.f;
#pragma unroll
        for (int j = 0; j < 8; ++j) {
            float4 wv = wrow[j];
            s += wv.x * pmk[j * 4 + 0] + wv.y * pmk[j * 4 + 1]
               + wv.z * pmk[j * 4 + 2] + wv.w * pmk[j * 4 + 3];
        }
        s += __shfl_down(s, 4, 8);
        s += __shfl_down(s, 2, 8);
        s += __shfl_down(s, 1, 8);
        if (k == 0) {
            float sig = 1.0f / (1.0f + __expf(-s));
            h_s[r] = s * sig;                // silu
        }
    }
    __syncthreads();

    // ---- Stage 4b: gate = sigmoid(w2 @ h); fold gamma/beta into gate ----
    {
        const int c = t;
        const float4* wrow = reinterpret_cast<const float4*>(w2 + c * R_DIM);
        float s = 0.f;
#pragma unroll
        for (int j = 0; j < 8; ++j) {
            float4 wv = wrow[j];
            s += wv.x * h_s[j * 4 + 0] + wv.y * h_s[j * 4 + 1]
               + wv.z * h_s[j * 4 + 2] + wv.w * h_s[j * 4 + 3];
        }
        float gate = 1.0f / (1.0f + __expf(-s));
        A_s[c] = g_c * gate;
        B_s[c] = b_c * gate;
    }
    __syncthreads();

    // ---- Stage 5: out = (gamma*rstd*(x-mu) + beta) * gate ----
#pragma unroll
    for (int it = 0; it < 16; ++it) {
        unsigned idx  = (unsigned)(it * 256 + t);
        unsigned c    = idx >> 4;
        unsigned h    = (idx >> 1) & 7;
        unsigned half = idx & 1;
        unsigned p0   = h * 8 + half * 4;
        float a  = A_s[c];
        float bb = B_s[c];
        const float* src = &xs[c * PAD + p0];
        float4 v;
        v.x = a * rs_s[p0 + 0] * (src[0] - mu_s[p0 + 0]) + bb;
        v.y = a * rs_s[p0 + 1] * (src[1] - mu_s[p0 + 1]) + bb;
        v.z = a * rs_s[p0 + 2] * (src[2] - mu_s[p0 + 2]) + bb;
        v.w = a * rs_s[p0 + 3] * (src[3] - mu_s[p0 + 3]) + bb;
        unsigned goff = baseb + (c * HWDIM + H0 + h) * HWDIM + W0 + half * 4u;
        *reinterpret_cast<float4*>(out + goff) = v;
    }
}

extern "C" void kernel_launch(void* const* d_in, const int* in_sizes, int n_in,
                              void* d_out, int out_size, void* d_ws, size_t ws_size,
                              hipStream_t stream) {
    const float* x     = (const float*)d_in[0];
    const float* gamma = (const float*)d_in[1];
    const float* beta  = (const float*)d_in[2];
    const float* w1    = (const float*)d_in[3];
    const float* w2    = (const float*)d_in[4];
    float* out = (float*)d_out;

    const int B = in_sizes[0] / (C_DIM * HWDIM * HWDIM);   // = 8
    const int nwg = B * (HWDIM / PATCH_SZ) * (HWDIM / PATCH_SZ);  // 8192

    lpa_fused_kernel<<<nwg, 256, 0, stream>>>(x, gamma, beta, w1, w2, out, nwg);
}